// Round 1
// baseline (775.405 us; speedup 1.0000x reference)
//
#include <hip/hip_runtime.h>

#define N_NODES 50000
#define E_EDGES 1600000
#define NHEAD 2
#define FDIM 32
#define HF 64           // NHEAD * FDIM
#define IN_F 32
#define OUT_F 32
#define NEG_SLOPE 0.2f

// ---------------- stage 1: node projections ----------------
// feat_src = feat @ W2s + b2s ; feat_dst = feat @ W2d + b2d  (both [N, 64])
// thread = (node, col); a wave covers all 64 cols of one node.
__global__ void proj_kernel(const float* __restrict__ feat,
                            const float* __restrict__ W2s, const float* __restrict__ b2s,
                            const float* __restrict__ W2d, const float* __restrict__ b2d,
                            float* __restrict__ fsrc, float* __restrict__ fdst) {
    int idx = blockIdx.x * blockDim.x + threadIdx.x;
    int n = idx >> 6;
    int c = idx & 63;
    if (n >= N_NODES) return;
    const float* frow = feat + n * IN_F;
    float s = b2s[c];
    float d = b2d[c];
    #pragma unroll
    for (int k = 0; k < IN_F; ++k) {
        float fv = frow[k];                  // broadcast within wave (same node)
        s += fv * W2s[k * HF + c];           // coalesced across lanes
        d += fv * W2d[k * HF + c];
    }
    fsrc[n * HF + c] = s;
    fdst[n * HF + c] = d;
}

// ---------------- stage 2: edge logits + softmax denominator ----------------
// wave per edge; lane = h*32 + f. e = sum_f leaky_relu(en+ev)*attn ; ee = exp(e)
__global__ void edge1_kernel(const int* __restrict__ src, const int* __restrict__ dst,
                             const float* __restrict__ fsrc, const float* __restrict__ fdst,
                             const float* __restrict__ attn,
                             float* __restrict__ ee, float* __restrict__ denom) {
    int tid = blockIdx.x * blockDim.x + threadIdx.x;
    int e = tid >> 6;
    int lane = threadIdx.x & 63;
    if (e >= E_EDGES) return;
    int s = src[e];
    int d = dst[e];
    float en = fsrc[s * HF + lane];
    float ev = fdst[d * HF + lane];
    float x = en + ev;
    x = (x > 0.0f) ? x : NEG_SLOPE * x;
    float v = x * attn[lane];
    // sum within each 32-lane half (one head per half)
    #pragma unroll
    for (int m = 1; m < 32; m <<= 1) v += __shfl_xor(v, m, 64);
    if ((lane & 31) == 0) {
        int h = lane >> 5;
        float ex = __expf(v);                 // max-sub skipped: |v| small, ratio identical
        ee[e * NHEAD + h] = ex;
        atomicAdd(&denom[d * NHEAD + h], ex);
    }
}

// ---------------- stage 3: message softmax + scatter ----------------
// wave per edge; lane = h*32 + f. msg = softmax_f(en * r_feat * alpha)
__global__ void edge2_kernel(const int* __restrict__ src, const int* __restrict__ dst,
                             const float* __restrict__ fsrc,
                             const float* __restrict__ r_feat,
                             const float* __restrict__ ee, const float* __restrict__ denom,
                             float* __restrict__ g_agg) {
    int tid = blockIdx.x * blockDim.x + threadIdx.x;
    int e = tid >> 6;
    int lane = threadIdx.x & 63;
    if (e >= E_EDGES) return;
    int s = src[e];
    int d = dst[e];
    int h = lane >> 5;
    float en = fsrc[s * HF + lane];                    // L2-resident gather
    float r  = r_feat[(size_t)e * HF + lane];          // coalesced 256B per edge
    float eev = ee[e * NHEAD + h];
    float den = denom[d * NHEAD + h];
    float alpha = eev / fmaxf(den, 1e-9f);
    float v = en * r * alpha;
    // softmax over the 32 lanes of this head
    float mx = v;
    #pragma unroll
    for (int m = 1; m < 32; m <<= 1) mx = fmaxf(mx, __shfl_xor(mx, m, 64));
    float p = __expf(v - mx);
    float sum = p;
    #pragma unroll
    for (int m = 1; m < 32; m <<= 1) sum += __shfl_xor(sum, m, 64);
    float msg = p / sum;
    atomicAdd(&g_agg[d * HF + lane], msg);
}

// ---------------- stage 4: output projection ----------------
// rst = (feat + sum_h g_agg) @ W1 + b1 ; thread = (node, out col)
__global__ void final_kernel(const float* __restrict__ feat,
                             const float* __restrict__ g_agg,
                             const float* __restrict__ W1, const float* __restrict__ b1,
                             float* __restrict__ out) {
    int idx = blockIdx.x * blockDim.x + threadIdx.x;
    int n = idx >> 5;
    int c = idx & 31;
    if (n >= N_NODES) return;
    float acc = b1[c];
    #pragma unroll
    for (int k = 0; k < IN_F; ++k) {
        float x = feat[n * IN_F + k] + g_agg[n * HF + k] + g_agg[n * HF + FDIM + k];
        acc += x * W1[k * OUT_F + c];
    }
    out[n * OUT_F + c] = acc;
}

extern "C" void kernel_launch(void* const* d_in, const int* in_sizes, int n_in,
                              void* d_out, int out_size, void* d_ws, size_t ws_size,
                              hipStream_t stream) {
    const float* feat  = (const float*)d_in[0];
    const float* rfeat = (const float*)d_in[1];
    const int*   src   = (const int*)d_in[2];
    const int*   dst   = (const int*)d_in[3];
    const float* W1    = (const float*)d_in[4];
    const float* b1    = (const float*)d_in[5];
    const float* W2s   = (const float*)d_in[6];
    const float* b2s   = (const float*)d_in[7];
    const float* W2d   = (const float*)d_in[8];
    const float* b2d   = (const float*)d_in[9];
    const float* attn  = (const float*)d_in[10];
    float* out = (float*)d_out;

    // workspace layout (f32 elements)
    float* fsrc  = (float*)d_ws;                       // N*64   = 3.2M
    float* fdst  = fsrc  + (size_t)N_NODES * HF;       // N*64
    float* ee    = fdst  + (size_t)N_NODES * HF;       // E*2    = 3.2M
    float* denom = ee    + (size_t)E_EDGES * NHEAD;    // N*2
    float* g_agg = denom + (size_t)N_NODES * NHEAD;    // N*64
    // total = 12.9M floats = 51.6 MB

    // zero the accumulators (ws is poisoned, not re-zeroed between replays)
    hipMemsetAsync(denom, 0, (size_t)N_NODES * NHEAD * sizeof(float), stream);
    hipMemsetAsync(g_agg, 0, (size_t)N_NODES * HF * sizeof(float), stream);

    const int BLK = 256;
    {   // stage 1
        int total = N_NODES * HF;
        proj_kernel<<<(total + BLK - 1) / BLK, BLK, 0, stream>>>(
            feat, W2s, b2s, W2d, b2d, fsrc, fdst);
    }
    {   // stage 2
        long long total = (long long)E_EDGES * 64;
        edge1_kernel<<<(unsigned)((total + BLK - 1) / BLK), BLK, 0, stream>>>(
            src, dst, fsrc, fdst, attn, ee, denom);
    }
    {   // stage 3
        long long total = (long long)E_EDGES * 64;
        edge2_kernel<<<(unsigned)((total + BLK - 1) / BLK), BLK, 0, stream>>>(
            src, dst, fsrc, rfeat, ee, denom, g_agg);
    }
    {   // stage 4
        int total = N_NODES * OUT_F;
        final_kernel<<<(total + BLK - 1) / BLK, BLK, 0, stream>>>(
            feat, g_agg, W1, b1, out);
    }
}

// Round 2
// 523.123 us; speedup vs baseline: 1.4823x; 1.4823x over previous
//
#include <hip/hip_runtime.h>

#define N_NODES 50000
#define E_EDGES 1600000
#define NHEAD 2
#define FDIM 32
#define HF 64           // NHEAD * FDIM
#define IN_F 32
#define OUT_F 32
#define NEG_SLOPE 0.2f
#define SCAN_BLK 512
#define NSCAN ((N_NODES + SCAN_BLK - 1) / SCAN_BLK)   // 98

// ---------- cross-lane reduction over each 32-lane half (all lanes get result)
template<int CTRL>
__device__ __forceinline__ float dpp_add(float v) {
    int t = __builtin_amdgcn_update_dpp(0, __float_as_int(v), CTRL, 0xf, 0xf, true);
    return v + __int_as_float(t);
}
__device__ __forceinline__ float red32_sum(float v) {
    v = dpp_add<0xB1>(v);    // quad_perm {1,0,3,2}  : xor1
    v = dpp_add<0x4E>(v);    // quad_perm {2,3,0,1}  : xor2
    v = dpp_add<0x141>(v);   // row_half_mirror      : pairs quads within 8
    v = dpp_add<0x140>(v);   // row_mirror           : pairs 8-groups within 16
    v += __int_as_float(__builtin_amdgcn_ds_swizzle(__float_as_int(v), 0x401F)); // xor16
    return v;
}

// ---------------- stage 1: node projections ----------------
__global__ void proj_kernel(const float* __restrict__ feat,
                            const float* __restrict__ W2s, const float* __restrict__ b2s,
                            const float* __restrict__ W2d, const float* __restrict__ b2d,
                            float* __restrict__ fsrc, float* __restrict__ fdst) {
    int idx = blockIdx.x * blockDim.x + threadIdx.x;
    int n = idx >> 6;
    int c = idx & 63;
    if (n >= N_NODES) return;
    const float* frow = feat + n * IN_F;
    float s = b2s[c];
    float d = b2d[c];
    #pragma unroll
    for (int k = 0; k < IN_F; ++k) {
        float fv = frow[k];
        s += fv * W2s[k * HF + c];
        d += fv * W2d[k * HF + c];
    }
    fsrc[n * HF + c] = s;
    fdst[n * HF + c] = d;
}

// ---------------- CSR build ----------------
__global__ void hist_kernel(const int* __restrict__ dst, int* __restrict__ deg) {
    int i = blockIdx.x * blockDim.x + threadIdx.x;
    if (i < E_EDGES) atomicAdd(&deg[dst[i]], 1);
}

__global__ void scan1_kernel(const int* __restrict__ deg, int* __restrict__ off,
                             int* __restrict__ bsum) {
    __shared__ int buf[SCAN_BLK];
    int tid = threadIdx.x;
    int i = blockIdx.x * SCAN_BLK + tid;
    int v = (i < N_NODES) ? deg[i] : 0;
    buf[tid] = v;
    __syncthreads();
    #pragma unroll
    for (int o = 1; o < SCAN_BLK; o <<= 1) {
        int t = (tid >= o) ? buf[tid - o] : 0;
        __syncthreads();
        buf[tid] += t;
        __syncthreads();
    }
    if (i < N_NODES) off[i] = buf[tid] - v;          // block-local exclusive
    if (tid == SCAN_BLK - 1) bsum[blockIdx.x] = buf[SCAN_BLK - 1];
}

__global__ void scan2_kernel(int* __restrict__ bsum) {
    __shared__ int buf[128];
    int tid = threadIdx.x;
    int v = (tid < NSCAN) ? bsum[tid] : 0;
    buf[tid] = v;
    __syncthreads();
    #pragma unroll
    for (int o = 1; o < 128; o <<= 1) {
        int t = (tid >= o) ? buf[tid - o] : 0;
        __syncthreads();
        buf[tid] += t;
        __syncthreads();
    }
    if (tid < NSCAN) bsum[tid] = buf[tid] - v;       // exclusive
}

__global__ void scan3_kernel(int* __restrict__ off, const int* __restrict__ bsum,
                             int* __restrict__ cur) {
    int i = blockIdx.x * blockDim.x + threadIdx.x;
    if (i < N_NODES) {
        int o = off[i] + bsum[i >> 9];               // SCAN_BLK = 512
        off[i] = o;
        cur[i] = o;
    }
    if (i == 0) off[N_NODES] = E_EDGES;
}

__global__ void scatter_kernel(const int* __restrict__ src, const int* __restrict__ dst,
                               int* __restrict__ cur,
                               int* __restrict__ eids, int* __restrict__ srcs) {
    int i = blockIdx.x * blockDim.x + threadIdx.x;
    if (i < E_EDGES) {
        int p = atomicAdd(&cur[dst[i]], 1);
        eids[p] = i;
        srcs[p] = src[i];
    }
}

// ---------------- stage 2: fused node-centric aggregate + output proj ----------------
// one wave per node; lane = h*32 + f
__global__ __launch_bounds__(256) void agg_kernel(
        const int* __restrict__ off, const int* __restrict__ eids,
        const int* __restrict__ srcs,
        const float* __restrict__ fsrc, const float* __restrict__ fdst,
        const float* __restrict__ rfeat, const float* __restrict__ attn,
        const float* __restrict__ feat,
        const float* __restrict__ W1, const float* __restrict__ b1,
        float* __restrict__ out) {
    int wid = (blockIdx.x * blockDim.x + threadIdx.x) >> 6;
    int lane = threadIdx.x & 63;
    if (wid >= N_NODES) return;
    int n = wid;
    int beg = off[n];
    int end = off[n + 1];
    float ev = fdst[n * HF + lane];
    float aw = attn[lane];

    // ---- pass A: edge-softmax denominator (per head, lane-uniform per half)
    float den = 0.0f;
    for (int base = beg; base < end; base += 64) {
        int cnt = min(64, end - base);
        int si = (base + lane < end) ? srcs[base + lane] : 0;
        for (int j = 0; j < cnt; ++j) {
            int s = __builtin_amdgcn_readlane(si, j);
            float en = fsrc[s * HF + lane];
            float x = en + ev;
            x = (x > 0.0f) ? x : NEG_SLOPE * x;
            float v = red32_sum(x * aw);             // logit, per 32-lane head
            den += __expf(v);                        // max-sub skipped: |v| small
        }
    }
    float dinv = __builtin_amdgcn_rcpf(fmaxf(den, 1e-9f));

    // ---- pass B: messages (recompute logit; feature softmax; accumulate g)
    float g = 0.0f;
    for (int base = beg; base < end; base += 64) {
        int cnt = min(64, end - base);
        bool ok = (base + lane < end);
        int si = ok ? srcs[base + lane] : 0;
        int ei = ok ? eids[base + lane] : 0;
        for (int j = 0; j < cnt; ++j) {
            int s = __builtin_amdgcn_readlane(si, j);
            int e = __builtin_amdgcn_readlane(ei, j);
            float en = fsrc[s * HF + lane];          // cache-hot (read in pass A)
            float x = en + ev;
            x = (x > 0.0f) ? x : NEG_SLOPE * x;
            float v0 = red32_sum(x * aw);
            float alpha = __expf(v0) * dinv;
            float r = rfeat[(size_t)e * HF + lane];  // streaming 256B
            float p = __expf(en * r * alpha);        // max-sub skipped: args small
            float ssum = red32_sum(p);
            g += p * __builtin_amdgcn_rcpf(ssum);
        }
    }

    // ---- epilogue: head sum + fused (feat + g_sum) @ W1 + b1
    float gs = g + __shfl_xor(g, 32, 64);            // g_sum[f] on lanes f and f+32
    int c = lane & 31;
    float x = feat[n * IN_F + c] + gs;               // x[k] held by lanes k and k+32
    float acc = b1[c];
    #pragma unroll
    for (int k = 0; k < 32; ++k) {
        float xk = __int_as_float(__builtin_amdgcn_readlane(__float_as_int(x), k));
        acc += xk * W1[k * OUT_F + c];
    }
    if (lane < 32) out[n * OUT_F + c] = acc;
}

extern "C" void kernel_launch(void* const* d_in, const int* in_sizes, int n_in,
                              void* d_out, int out_size, void* d_ws, size_t ws_size,
                              hipStream_t stream) {
    const float* feat  = (const float*)d_in[0];
    const float* rfeat = (const float*)d_in[1];
    const int*   src   = (const int*)d_in[2];
    const int*   dst   = (const int*)d_in[3];
    const float* W1    = (const float*)d_in[4];
    const float* b1    = (const float*)d_in[5];
    const float* W2s   = (const float*)d_in[6];
    const float* b2s   = (const float*)d_in[7];
    const float* W2d   = (const float*)d_in[8];
    const float* b2d   = (const float*)d_in[9];
    const float* attn  = (const float*)d_in[10];
    float* out = (float*)d_out;

    // workspace layout
    float* fsrc = (float*)d_ws;                           // N*64
    float* fdst = fsrc + (size_t)N_NODES * HF;            // N*64
    int*   deg  = (int*)(fdst + (size_t)N_NODES * HF);    // N
    int*   off  = deg + N_NODES;                          // N+1
    int*   cur  = off + N_NODES + 1;                      // N
    int*   bsum = cur + N_NODES;                          // 128
    int*   eids = bsum + 128;                             // E
    int*   srcs = eids + E_EDGES;                         // E
    // total ~ 39 MB

    hipMemsetAsync(deg, 0, (size_t)N_NODES * sizeof(int), stream);

    const int BLK = 256;
    proj_kernel<<<(N_NODES * HF + BLK - 1) / BLK, BLK, 0, stream>>>(
        feat, W2s, b2s, W2d, b2d, fsrc, fdst);
    hist_kernel<<<(E_EDGES + BLK - 1) / BLK, BLK, 0, stream>>>(dst, deg);
    scan1_kernel<<<NSCAN, SCAN_BLK, 0, stream>>>(deg, off, bsum);
    scan2_kernel<<<1, 128, 0, stream>>>(bsum);
    scan3_kernel<<<(N_NODES + BLK - 1) / BLK, BLK, 0, stream>>>(off, bsum, cur);
    scatter_kernel<<<(E_EDGES + BLK - 1) / BLK, BLK, 0, stream>>>(
        src, dst, cur, eids, srcs);
    agg_kernel<<<(N_NODES * 64 + BLK - 1) / BLK, BLK, 0, stream>>>(
        off, eids, srcs, fsrc, fdst, rfeat, attn, feat, W1, b1, out);
}

// Round 3
// 413.877 us; speedup vs baseline: 1.8735x; 1.2640x over previous
//
#include <hip/hip_runtime.h>

#define N_NODES 50000
#define E_EDGES 1600000
#define NHEAD 2
#define FDIM 32
#define HF 64           // NHEAD * FDIM
#define IN_F 32
#define OUT_F 32
#define NEG_SLOPE 0.2f
#define SCAN_BLK 512
#define NSCAN ((N_NODES + SCAN_BLK - 1) / SCAN_BLK)   // 98
#define CAP 512         // per-wave LDS cache of exp(logit), edges per node

// ---------- cross-lane reduction over each 32-lane half (all lanes get result)
template<int CTRL>
__device__ __forceinline__ float dpp_add(float v) {
    int t = __builtin_amdgcn_update_dpp(0, __float_as_int(v), CTRL, 0xf, 0xf, true);
    return v + __int_as_float(t);
}
__device__ __forceinline__ float red32_sum(float v) {
    v = dpp_add<0xB1>(v);    // xor1 (quad_perm)
    v = dpp_add<0x4E>(v);    // xor2 (quad_perm)
    v = dpp_add<0x141>(v);   // row_half_mirror
    v = dpp_add<0x140>(v);   // row_mirror
    v += __int_as_float(__builtin_amdgcn_ds_swizzle(__float_as_int(v), 0x401F)); // xor16
    return v;
}
__device__ __forceinline__ int rl(int v, int l) { return __builtin_amdgcn_readlane(v, l); }
__device__ __forceinline__ float lrelu(float x) { return x > 0.f ? x : NEG_SLOPE * x; }

// ---------------- stage 1: node projections ----------------
__global__ void proj_kernel(const float* __restrict__ feat,
                            const float* __restrict__ W2s, const float* __restrict__ b2s,
                            const float* __restrict__ W2d, const float* __restrict__ b2d,
                            float* __restrict__ fsrc, float* __restrict__ fdst) {
    int idx = blockIdx.x * blockDim.x + threadIdx.x;
    int n = idx >> 6;
    int c = idx & 63;
    if (n >= N_NODES) return;
    const float* frow = feat + n * IN_F;
    float s = b2s[c];
    float d = b2d[c];
    #pragma unroll
    for (int k = 0; k < IN_F; ++k) {
        float fv = frow[k];
        s += fv * W2s[k * HF + c];
        d += fv * W2d[k * HF + c];
    }
    fsrc[n * HF + c] = s;
    fdst[n * HF + c] = d;
}

// ---------------- CSR build ----------------
__global__ void hist_kernel(const int* __restrict__ dst, int* __restrict__ deg) {
    int i = blockIdx.x * blockDim.x + threadIdx.x;
    if (i * 2 < E_EDGES) {
        int2 d = ((const int2*)dst)[i];
        atomicAdd(&deg[d.x], 1);
        atomicAdd(&deg[d.y], 1);
    }
}

__global__ void scan1_kernel(const int* __restrict__ deg, int* __restrict__ off,
                             int* __restrict__ bsum) {
    __shared__ int buf[SCAN_BLK];
    int tid = threadIdx.x;
    int i = blockIdx.x * SCAN_BLK + tid;
    int v = (i < N_NODES) ? deg[i] : 0;
    buf[tid] = v;
    __syncthreads();
    #pragma unroll
    for (int o = 1; o < SCAN_BLK; o <<= 1) {
        int t = (tid >= o) ? buf[tid - o] : 0;
        __syncthreads();
        buf[tid] += t;
        __syncthreads();
    }
    if (i < N_NODES) off[i] = buf[tid] - v;
    if (tid == SCAN_BLK - 1) bsum[blockIdx.x] = buf[SCAN_BLK - 1];
}

__global__ void scan2_kernel(int* __restrict__ bsum) {
    __shared__ int buf[128];
    int tid = threadIdx.x;
    int v = (tid < NSCAN) ? bsum[tid] : 0;
    buf[tid] = v;
    __syncthreads();
    #pragma unroll
    for (int o = 1; o < 128; o <<= 1) {
        int t = (tid >= o) ? buf[tid - o] : 0;
        __syncthreads();
        buf[tid] += t;
        __syncthreads();
    }
    if (tid < NSCAN) bsum[tid] = buf[tid] - v;
}

__global__ void scan3_kernel(int* __restrict__ off, const int* __restrict__ bsum,
                             int* __restrict__ cur) {
    int i = blockIdx.x * blockDim.x + threadIdx.x;
    if (i < N_NODES) {
        int o = off[i] + bsum[i >> 9];
        off[i] = o;
        cur[i] = o;
    }
    if (i == 0) off[N_NODES] = E_EDGES;
}

__global__ void scatter_kernel(const int* __restrict__ src, const int* __restrict__ dst,
                               int* __restrict__ cur, int2* __restrict__ pairs) {
    int i = blockIdx.x * blockDim.x + threadIdx.x;
    if (i < E_EDGES) {
        int p = atomicAdd(&cur[dst[i]], 1);
        pairs[p] = make_int2(src[i], i);
    }
}

// ---------------- fused node-centric aggregate + output proj ----------------
// one wave per node; lane = h*32 + f; 4-edge batched inner loops for MLP
__global__ __launch_bounds__(256) void agg_kernel(
        const int* __restrict__ off, const int2* __restrict__ pairs,
        const float* __restrict__ fsrc, const float* __restrict__ fdst,
        const float* __restrict__ rfeat, const float* __restrict__ attn,
        const float* __restrict__ feat,
        const float* __restrict__ W1, const float* __restrict__ b1,
        float* __restrict__ out) {
    __shared__ float eeL_all[4][CAP * NHEAD];
    int tid = threadIdx.x;
    float* eeL = eeL_all[tid >> 6];
    int wid = (blockIdx.x * blockDim.x + tid) >> 6;
    if (wid >= N_NODES) return;     // no __syncthreads below: wave-private LDS only
    int lane = tid & 63;
    int n = wid;
    int beg = off[n];
    int end = off[n + 1];
    int deg = end - beg;
    float ev = fdst[n * HF + lane];
    float aw = attn[lane];
    int h = lane >> 5;
    bool wlead = (lane & 31) == 0;  // lanes 0 and 32 own the per-head scalar

    // ---- pass A: per-edge exp(logit) -> LDS; denominator in 4 partial accs
    float dA0 = 0, dA1 = 0, dA2 = 0, dA3 = 0;
    for (int base = beg; base < end; base += 64) {
        int cnt = min(64, end - base);
        int si = (lane < cnt) ? pairs[base + lane].x : 0;
        int j = 0;
        for (; j + 4 <= cnt; j += 4) {
            int s0 = rl(si, j), s1 = rl(si, j + 1), s2 = rl(si, j + 2), s3 = rl(si, j + 3);
            float en0 = fsrc[s0 * HF + lane];
            float en1 = fsrc[s1 * HF + lane];
            float en2 = fsrc[s2 * HF + lane];
            float en3 = fsrc[s3 * HF + lane];
            float v0 = red32_sum(lrelu(en0 + ev) * aw);
            float v1 = red32_sum(lrelu(en1 + ev) * aw);
            float v2 = red32_sum(lrelu(en2 + ev) * aw);
            float v3 = red32_sum(lrelu(en3 + ev) * aw);
            float E0 = __expf(v0), E1 = __expf(v1), E2 = __expf(v2), E3 = __expf(v3);
            int ide = base - beg + j;
            if (wlead) {
                if (ide + 0 < CAP) eeL[(ide + 0) * NHEAD + h] = E0;
                if (ide + 1 < CAP) eeL[(ide + 1) * NHEAD + h] = E1;
                if (ide + 2 < CAP) eeL[(ide + 2) * NHEAD + h] = E2;
                if (ide + 3 < CAP) eeL[(ide + 3) * NHEAD + h] = E3;
            }
            dA0 += E0; dA1 += E1; dA2 += E2; dA3 += E3;
        }
        for (; j < cnt; ++j) {
            int s = rl(si, j);
            float en = fsrc[s * HF + lane];
            float v = red32_sum(lrelu(en + ev) * aw);
            float E = __expf(v);
            int ide = base - beg + j;
            if (wlead && ide < CAP) eeL[ide * NHEAD + h] = E;
            dA0 += E;
        }
    }
    float den = (dA0 + dA1) + (dA2 + dA3);
    float dinv = __builtin_amdgcn_rcpf(fmaxf(den, 1e-9f));

    // ---- pass B: messages (alpha from LDS); feature softmax; accumulate g
    float g0 = 0, g1 = 0, g2 = 0, g3 = 0;
    if (deg <= CAP) {
        for (int base = beg; base < end; base += 64) {
            int cnt = min(64, end - base);
            int2 es = (lane < cnt) ? pairs[base + lane] : make_int2(0, 0);
            int j = 0;
            for (; j + 4 <= cnt; j += 4) {
                int s0 = rl(es.x, j), s1 = rl(es.x, j + 1), s2 = rl(es.x, j + 2), s3 = rl(es.x, j + 3);
                int e0 = rl(es.y, j), e1 = rl(es.y, j + 1), e2 = rl(es.y, j + 2), e3 = rl(es.y, j + 3);
                float en0 = fsrc[s0 * HF + lane];
                float en1 = fsrc[s1 * HF + lane];
                float en2 = fsrc[s2 * HF + lane];
                float en3 = fsrc[s3 * HF + lane];
                float r0 = rfeat[(size_t)e0 * HF + lane];
                float r1 = rfeat[(size_t)e1 * HF + lane];
                float r2 = rfeat[(size_t)e2 * HF + lane];
                float r3 = rfeat[(size_t)e3 * HF + lane];
                int ide = base - beg + j;
                float a0 = eeL[(ide + 0) * NHEAD + h] * dinv;
                float a1 = eeL[(ide + 1) * NHEAD + h] * dinv;
                float a2 = eeL[(ide + 2) * NHEAD + h] * dinv;
                float a3 = eeL[(ide + 3) * NHEAD + h] * dinv;
                float p0 = __expf(en0 * r0 * a0);
                float p1 = __expf(en1 * r1 * a1);
                float p2 = __expf(en2 * r2 * a2);
                float p3 = __expf(en3 * r3 * a3);
                float S0 = red32_sum(p0);
                float S1 = red32_sum(p1);
                float S2 = red32_sum(p2);
                float S3 = red32_sum(p3);
                g0 += p0 * __builtin_amdgcn_rcpf(S0);
                g1 += p1 * __builtin_amdgcn_rcpf(S1);
                g2 += p2 * __builtin_amdgcn_rcpf(S2);
                g3 += p3 * __builtin_amdgcn_rcpf(S3);
            }
            for (; j < cnt; ++j) {
                int s = rl(es.x, j), e = rl(es.y, j);
                float en = fsrc[s * HF + lane];
                float r = rfeat[(size_t)e * HF + lane];
                int ide = base - beg + j;
                float a = eeL[ide * NHEAD + h] * dinv;
                float p = __expf(en * r * a);
                float S = red32_sum(p);
                g0 += p * __builtin_amdgcn_rcpf(S);
            }
        }
    } else {
        // slow fallback (deg > CAP): recompute alpha per edge. Correct, ~never taken.
        for (int base = beg; base < end; base += 64) {
            int cnt = min(64, end - base);
            int2 es = (lane < cnt) ? pairs[base + lane] : make_int2(0, 0);
            for (int j = 0; j < cnt; ++j) {
                int s = rl(es.x, j), e = rl(es.y, j);
                float en = fsrc[s * HF + lane];
                float v = red32_sum(lrelu(en + ev) * aw);
                float a = __expf(v) * dinv;
                float r = rfeat[(size_t)e * HF + lane];
                float p = __expf(en * r * a);
                float S = red32_sum(p);
                g0 += p * __builtin_amdgcn_rcpf(S);
            }
        }
    }
    float g = (g0 + g1) + (g2 + g3);

    // ---- epilogue: head sum + fused (feat + g_sum) @ W1 + b1
    float gs = g + __shfl_xor(g, 32, 64);
    int c = lane & 31;
    float x = feat[n * IN_F + c] + gs;
    float acc = b1[c];
    #pragma unroll
    for (int k = 0; k < 32; ++k) {
        float xk = __int_as_float(rl(__float_as_int(x), k));
        acc += xk * W1[k * OUT_F + c];
    }
    if (lane < 32) out[n * OUT_F + c] = acc;
}

extern "C" void kernel_launch(void* const* d_in, const int* in_sizes, int n_in,
                              void* d_out, int out_size, void* d_ws, size_t ws_size,
                              hipStream_t stream) {
    const float* feat  = (const float*)d_in[0];
    const float* rfeat = (const float*)d_in[1];
    const int*   src   = (const int*)d_in[2];
    const int*   dst   = (const int*)d_in[3];
    const float* W1    = (const float*)d_in[4];
    const float* b1    = (const float*)d_in[5];
    const float* W2s   = (const float*)d_in[6];
    const float* b2s   = (const float*)d_in[7];
    const float* W2d   = (const float*)d_in[8];
    const float* b2d   = (const float*)d_in[9];
    const float* attn  = (const float*)d_in[10];
    float* out = (float*)d_out;

    // workspace layout
    float* fsrc = (float*)d_ws;                           // N*64
    float* fdst = fsrc + (size_t)N_NODES * HF;            // N*64
    int*   deg  = (int*)(fdst + (size_t)N_NODES * HF);    // N
    int*   off  = deg + N_NODES;                          // N+1
    int*   cur  = off + N_NODES + 1;                      // N
    int*   bsum = cur + N_NODES;                          // 128
    int2*  pairs = (int2*)(bsum + 128 + 1);               // E int2 (8B-aligned: offset is even # of ints)
    // total ~ 39 MB

    hipMemsetAsync(deg, 0, (size_t)N_NODES * sizeof(int), stream);

    const int BLK = 256;
    proj_kernel<<<(N_NODES * HF + BLK - 1) / BLK, BLK, 0, stream>>>(
        feat, W2s, b2s, W2d, b2d, fsrc, fdst);
    hist_kernel<<<(E_EDGES / 2 + BLK - 1) / BLK, BLK, 0, stream>>>(dst, deg);
    scan1_kernel<<<NSCAN, SCAN_BLK, 0, stream>>>(deg, off, bsum);
    scan2_kernel<<<1, 128, 0, stream>>>(bsum);
    scan3_kernel<<<(N_NODES + BLK - 1) / BLK, BLK, 0, stream>>>(off, bsum, cur);
    scatter_kernel<<<(E_EDGES + BLK - 1) / BLK, BLK, 0, stream>>>(
        src, dst, cur, pairs);
    agg_kernel<<<(N_NODES * 64 + BLK - 1) / BLK, BLK, 0, stream>>>(
        off, pairs, fsrc, fdst, rfeat, attn, feat, W1, b1, out);
}